// Round 5
// baseline (147.374 us; speedup 1.0000x reference)
//
#include <hip/hip_runtime.h>

// ---------- bf16 pack helper (raw ushort representation) ----------
__device__ __forceinline__ unsigned short f2b(float f) {
    unsigned int u = __builtin_bit_cast(unsigned int, f);
    u += 0x7fffu + ((u >> 16) & 1u);   // round-to-nearest-even
    return (unsigned short)(u >> 16);
}

typedef short bf16x8_t __attribute__((ext_vector_type(8)));
typedef float f32x4_t  __attribute__((ext_vector_type(4)));

#define LDS_PTR(p) ((__attribute__((address_space(3))) void*)(p))
#define GLB_PTR(p) ((const __attribute__((address_space(1))) void*)(p))

// Problem dims
#define NB   16384   // batch
#define AD   1024    // A dim
#define YD   128     // output dim
#define ND   256     // GEMM N = 2*YD
#define BM   32      // rows per block

// =====================================================================
// Kernel 1: Vt[n][a] = Kq[a,j]^2 * u[2a+j][y],  n = j*128+y  (bf16, K-major)
// =====================================================================
__global__ __launch_bounds__(256) void vt_kernel(
    const float* __restrict__ Kq,    // [1024][2] f32
    const float* __restrict__ U,     // [2048][128] f32
    unsigned short* __restrict__ Vt) // [256][1024] bf16
{
    int idx = blockIdx.x * 256 + threadIdx.x;   // 0 .. 262143
    int n = idx >> 10;
    int a = idx & 1023;
    int j = n >> 7;
    int y = n & 127;
    float k  = Kq[2 * a + j];
    float uv = U[(size_t)(2 * a + j) * YD + y];
    Vt[idx] = f2b(k * k * uv);
}

// =====================================================================
// Kernel 2: fully fused. Per block (512 thr, 8 waves, BM=32 rows):
//  phase 1: stream 32 rows of AT once -> 9 moments/row (16-lane shfl
//           reduce) -> closed-form bf fixed point (validated R2 math).
//  phase 2: re-read A (L2-hot), weight w = 1-x+x^2 (validated R4 poly),
//           pack weighted bf16 A into 32 VGPRs (pk[16][2]); thread chunk
//           c == K-tile index, so each K-iter is fed from registers.
//  phase 3: K-loop, double-buffered lB (global_load_lds w=16) + lAb
//           (ds_write from pk), ONE barrier/iter -> B(k+1) flies during
//           MFMA(k). Epilogue fuses out = bf0*G[y] + bf1*G[y+128] + bias.
// LDS: lB dbuf 64K + lAb dbuf 8K + bfs 256B = 72.25K -> 2 blocks/CU.
// kpp (8K) overlays lB[0] (dead before first B stage).
// =====================================================================
__global__ __launch_bounds__(512, 4) void fused_kernel(
    const float* __restrict__ AT,          // [16384][1024] f32
    const float* __restrict__ Kq,          // [1024][2] f32
    const float* __restrict__ BTv,         // [2] f32
    const unsigned short* __restrict__ Bg, // Vt [256][1024] bf16
    const float* __restrict__ bias,        // [128] f32
    float* __restrict__ out)               // [16384][128] f32
{
    __shared__ __align__(16) unsigned short lB[2][256 * 64];  // 64 KB
    __shared__ __align__(16) unsigned short lAb[2][32 * 64];  // 8 KB
    __shared__ float bfs[BM][2];                              // 256 B
    float* kpp = (float*)&lB[0][0];   // 8 KB overlay, phase-1/2 only

    const int t    = threadIdx.x;
    const int mtile = blockIdx.x;     // 0..511
    const int r    = t >> 4;          // row 0..31
    const int li   = t & 15;          // lane-in-row
    const int lane = t & 63;
    const int w    = t >> 6;          // wave 0..7

    // kpp[2a+j] = Kq[2a+j]^2
    {
        float4 kv = *(const float4*)(Kq + t * 4);
        *(float4*)(kpp + t * 4) =
            make_float4(kv.x * kv.x, kv.y * kv.y, kv.z * kv.z, kv.w * kv.w);
    }
    __syncthreads();

    const float* aRow = AT + (size_t)(mtile * BM + r) * AD + li * 4;

    // ---- phase 1: moments (thread covers cols c*64 + li*4 + e) ----
    float M[9];
#pragma unroll
    for (int i = 0; i < 9; ++i) M[i] = 0.f;
#pragma unroll
    for (int c = 0; c < 16; ++c) {
        float4 a = *(const float4*)(aRow + c * 64);
        const float* kp = kpp + 2 * (c * 64 + li * 4);
        float4 kA = *(const float4*)(kp);
        float4 kB = *(const float4*)(kp + 4);
        float ae[4] = {a.x, a.y, a.z, a.w};
        float pe[4] = {kA.x, kA.z, kB.x, kB.z};
        float qe[4] = {kA.y, kA.w, kB.y, kB.w};
#pragma unroll
        for (int e = 0; e < 4; ++e) {
            float tt = ae[e], p = pe[e], q = qe[e];
            float u0 = tt * p, u1 = tt * q;
            M[0] += u0; M[1] += u1;
            float u00 = u0 * p, u01 = u0 * q, u11 = u1 * q;
            M[2] += u00; M[3] += u01; M[4] += u11;
            M[5] += u00 * p; M[6] += u00 * q; M[7] += u01 * q; M[8] += u11 * q;
        }
    }
    // 16-lane reduce (rows are lane-groups of 16 within a wave)
#pragma unroll
    for (int i = 0; i < 9; ++i) {
        M[i] += __shfl_xor(M[i], 1, 64);
        M[i] += __shfl_xor(M[i], 2, 64);
        M[i] += __shfl_xor(M[i], 4, 64);
        M[i] += __shfl_xor(M[i], 8, 64);
    }
    float bt0 = BTv[0], bt1 = BTv[1];
    float bf0 = 0.f, bf1 = 0.f;
#pragma unroll
    for (int it = 0; it < 8; ++it) {
        float q00 = bf0 * bf0, q01 = bf0 * bf1, q11 = bf1 * bf1;
        float s0 = M[0] - (bf0 * M[2] + bf1 * M[3]) + (q00 * M[5] + 2.f * q01 * M[6] + q11 * M[7]);
        float s1 = M[1] - (bf0 * M[3] + bf1 * M[4]) + (q00 * M[6] + 2.f * q01 * M[7] + q11 * M[8]);
        bf0 = bt0 / (1.f + s0);
        bf1 = bt1 / (1.f + s1);
    }
    if (li == 0) { bfs[r][0] = bf0; bfs[r][1] = bf1; }

    // ---- phase 2: re-read A (L2-hot), weight, pack to 32 VGPRs ----
    unsigned int pk[16][2];
#pragma unroll
    for (int c = 0; c < 16; ++c) {
        float4 a = *(const float4*)(aRow + c * 64);
        const float* kp = kpp + 2 * (c * 64 + li * 4);
        float4 kA = *(const float4*)(kp);
        float4 kB = *(const float4*)(kp + 4);
        float ae[4] = {a.x, a.y, a.z, a.w};
        float pe[4] = {kA.x, kA.z, kB.x, kB.z};
        float qe[4] = {kA.y, kA.w, kB.y, kB.w};
        unsigned short rs[4];
#pragma unroll
        for (int e = 0; e < 4; ++e) {
            float x  = bf0 * pe[e] + bf1 * qe[e];
            float wg = x * (x - 1.f) + 1.f;       // 1 - x + x^2
            rs[e] = f2b(ae[e] * wg);
        }
        pk[c][0] = (unsigned int)rs[0] | ((unsigned int)rs[1] << 16);
        pk[c][1] = (unsigned int)rs[2] | ((unsigned int)rs[3] << 16);
    }
    __syncthreads();   // kpp reads done -> lB[0] reusable; bfs visible

    // ---- phase 3: K-loop ----
    const unsigned short* gBp[4];
#pragma unroll
    for (int i = 0; i < 4; ++i) {
        int s = i * 512 + t;
        int n = s >> 3;
        int c = s & 7;
        gBp[i] = Bg + (size_t)n * AD + 8 * (c ^ (n & 7));  // slot s holds chunk (s&7)^(n&7)
    }
    // A write addr: tile chunk li>>1 of row r, half li&1 (swizzled)
    const int aws = (r * 8 + ((li >> 1) ^ (r & 7))) * 8 + (li & 1) * 4;

    // prologue: stage tile 0
#pragma unroll
    for (int i = 0; i < 4; ++i)
        __builtin_amdgcn_global_load_lds(GLB_PTR(gBp[i]), LDS_PTR(&lB[0][(i * 512 + t) * 8]), 16, 0, 0);
    *(uint2*)&lAb[0][aws] = make_uint2(pk[0][0], pk[0][1]);
    __syncthreads();

    f32x4_t acc[2][2];
#pragma unroll
    for (int i = 0; i < 2; ++i)
#pragma unroll
        for (int j = 0; j < 2; ++j) acc[i][j] = (f32x4_t){0.f, 0.f, 0.f, 0.f};

    const int rr = lane & 15, q4 = lane >> 4;

#pragma unroll
    for (int kt = 0; kt < 16; ++kt) {
        const int buf = kt & 1;
        if (kt + 1 < 16) {
#pragma unroll
            for (int i = 0; i < 4; ++i)
                __builtin_amdgcn_global_load_lds(GLB_PTR(gBp[i] + (kt + 1) * 64),
                                                 LDS_PTR(&lB[buf ^ 1][(i * 512 + t) * 8]), 16, 0, 0);
            *(uint2*)&lAb[buf ^ 1][aws] = make_uint2(pk[kt + 1][0], pk[kt + 1][1]);
        }
#pragma unroll
        for (int kk = 0; kk < 2; ++kk) {
            const int cq = kk * 4 + q4;
            bf16x8_t fa[2], fb[2];
#pragma unroll
            for (int i = 0; i < 2; ++i) {
                int m = i * 16 + rr;
                fa[i] = *(const bf16x8_t*)(&lAb[buf][(m * 8 + (cq ^ (m & 7))) * 8]);
            }
#pragma unroll
            for (int j = 0; j < 2; ++j) {
                int n = j * 128 + w * 16 + rr;
                fb[j] = *(const bf16x8_t*)(&lB[buf][(n * 8 + (cq ^ (n & 7))) * 8]);
            }
#pragma unroll
            for (int i = 0; i < 2; ++i)
#pragma unroll
                for (int j = 0; j < 2; ++j)
                    acc[i][j] = __builtin_amdgcn_mfma_f32_16x16x32_bf16(fa[i], fb[j], acc[i][j], 0, 0, 0);
        }
        __syncthreads();   // drains next tile's B loads + lAb write; protects buf reuse
    }

    // ---- epilogue: C/D layout col=lane&15 (n), row=q4*4+reg (m) ----
    // wave w owns y in [w*16, w*16+16); acc[i][1] is the n = y+128 partner.
#pragma unroll
    for (int i = 0; i < 2; ++i) {
#pragma unroll
        for (int rt = 0; rt < 4; ++rt) {
            int ml = i * 16 + q4 * 4 + rt;
            int y  = w * 16 + rr;
            float v = bfs[ml][0] * acc[i][0][rt] + bfs[ml][1] * acc[i][1][rt] + bias[y];
            out[(size_t)(mtile * BM + ml) * YD + y] = v;
        }
    }
}

// =====================================================================
extern "C" void kernel_launch(void* const* d_in, const int* in_sizes, int n_in,
                              void* d_out, int out_size, void* d_ws, size_t ws_size,
                              hipStream_t stream) {
    const float* AT  = (const float*)d_in[0];  // [16384][1024] f32
    const float* Kq  = (const float*)d_in[1];  // [1024][2] f32
    const float* BTv = (const float*)d_in[2];  // [2] f32
    const float* U   = (const float*)d_in[3];  // [2048][128] f32
    const float* bia = (const float*)d_in[4];  // [128] f32
    float* out = (float*)d_out;

    unsigned short* Vt = (unsigned short*)d_ws;   // 512 KB bf16 [256][1024]

    vt_kernel<<<dim3(1024), dim3(256), 0, stream>>>(Kq, U, Vt);
    fused_kernel<<<dim3(NB / BM), dim3(512), 0, stream>>>(AT, Kq, BTv, Vt, bia, out);
}

// Round 6
// 133.271 us; speedup vs baseline: 1.1058x; 1.1058x over previous
//
#include <hip/hip_runtime.h>

// ---------- bf16 helpers (raw ushort representation) ----------
__device__ __forceinline__ float b2f(unsigned short h) {
    unsigned int u = ((unsigned int)h) << 16;
    return __builtin_bit_cast(float, u);
}
__device__ __forceinline__ unsigned short f2b(float f) {
    unsigned int u = __builtin_bit_cast(unsigned int, f);
    u += 0x7fffu + ((u >> 16) & 1u);   // round-to-nearest-even
    return (unsigned short)(u >> 16);
}

typedef short bf16x8_t __attribute__((ext_vector_type(8)));
typedef float f32x4_t  __attribute__((ext_vector_type(4)));

#define LDS_PTR(p) ((__attribute__((address_space(3))) void*)(p))
#define GLB_PTR(p) ((const __attribute__((address_space(1))) void*)(p))

// Problem dims
#define NB   16384   // batch
#define AD   1024    // A dim
#define YD   128     // output dim
#define ND   256     // GEMM N = 2*YD
#define BM   32      // rows per block

// =====================================================================
// Kernel 1: Vt[n][a] = Kq[a,j]^2 * u[2a+j][y],  n = j*128+y  (bf16, K-major)
// =====================================================================
__global__ __launch_bounds__(256) void vt_kernel(
    const float* __restrict__ Kq,    // [1024][2] f32
    const float* __restrict__ U,     // [2048][128] f32
    unsigned short* __restrict__ Vt) // [256][1024] bf16
{
    int idx = blockIdx.x * 256 + threadIdx.x;   // 0 .. 262143
    int n = idx >> 10;
    int a = idx & 1023;
    int j = n >> 7;
    int y = n & 127;
    float k  = Kq[2 * a + j];
    float uv = U[(size_t)(2 * a + j) * YD + y];
    Vt[idx] = f2b(k * k * uv);
}

// =====================================================================
// Kernel 2: fully fused (R5 structure, spill-fixed).
//  phase 1: stream 32 rows of AT ONCE -> f32 moments (R2-validated math)
//           AND pack raw bf16 A into pk[16][2] (32 VGPRs).
//  bf solve: 16-lane shfl reduce + closed-form fixed point.
//  phase 2: register-only: unpack pk, w = x*(x-1)+1 (R4-validated poly),
//           repack. No second A pass.
//  phase 3: K-loop, double-buffered lB (global_load_lds w=16) + lAb
//           (ds_write from pk), one barrier/iter. Fused combine epilogue.
// LDS: lB dbuf 64K + lAb dbuf 8K + bfs 256B = 72.25K -> 2 blocks/CU.
// __launch_bounds__(512,2): 256-VGPR headroom so pk is NOT spilled
// (R5's (512,4) produced VGPR_Count=64 + 66 MB scratch traffic).
// =====================================================================
__global__ __launch_bounds__(512, 2) void fused_kernel(
    const float* __restrict__ AT,          // [16384][1024] f32
    const float* __restrict__ Kq,          // [1024][2] f32
    const float* __restrict__ BTv,         // [2] f32
    const unsigned short* __restrict__ Bg, // Vt [256][1024] bf16
    const float* __restrict__ bias,        // [128] f32
    float* __restrict__ out)               // [16384][128] f32
{
    __shared__ __align__(16) unsigned short lB[2][256 * 64];  // 64 KB
    __shared__ __align__(16) unsigned short lAb[2][32 * 64];  // 8 KB
    __shared__ float bfs[BM][2];                              // 256 B
    float* kpp = (float*)&lB[0][0];   // 8 KB overlay, phase-1/2 only

    const int t    = threadIdx.x;
    const int mtile = blockIdx.x;     // 0..511
    const int r    = t >> 4;          // row 0..31
    const int li   = t & 15;          // lane-in-row
    const int lane = t & 63;
    const int w    = t >> 6;          // wave 0..7

    // kpp[2a+j] = Kq[2a+j]^2
    {
        float4 kv = *(const float4*)(Kq + t * 4);
        *(float4*)(kpp + t * 4) =
            make_float4(kv.x * kv.x, kv.y * kv.y, kv.z * kv.z, kv.w * kv.w);
    }
    __syncthreads();

    const float* aRow = AT + (size_t)(mtile * BM + r) * AD + li * 4;

    // ---- phase 1: single A pass -> moments (f32) + raw bf16 pack ----
    unsigned int pk[16][2];
    float M[9];
#pragma unroll
    for (int i = 0; i < 9; ++i) M[i] = 0.f;
#pragma unroll
    for (int c = 0; c < 16; ++c) {
        float4 a = *(const float4*)(aRow + c * 64);
        const float* kp = kpp + 2 * (c * 64 + li * 4);
        float4 kA = *(const float4*)(kp);
        float4 kB = *(const float4*)(kp + 4);
        float ae[4] = {a.x, a.y, a.z, a.w};
        float pe[4] = {kA.x, kA.z, kB.x, kB.z};
        float qe[4] = {kA.y, kA.w, kB.y, kB.w};
#pragma unroll
        for (int e = 0; e < 4; ++e) {
            float tt = ae[e], p = pe[e], q = qe[e];
            float u0 = tt * p, u1 = tt * q;
            M[0] += u0; M[1] += u1;
            float u00 = u0 * p, u01 = u0 * q, u11 = u1 * q;
            M[2] += u00; M[3] += u01; M[4] += u11;
            M[5] += u00 * p; M[6] += u00 * q; M[7] += u01 * q; M[8] += u11 * q;
        }
        pk[c][0] = (unsigned int)f2b(ae[0]) | ((unsigned int)f2b(ae[1]) << 16);
        pk[c][1] = (unsigned int)f2b(ae[2]) | ((unsigned int)f2b(ae[3]) << 16);
    }
    // 16-lane reduce (rows are lane-groups of 16 within a wave)
#pragma unroll
    for (int i = 0; i < 9; ++i) {
        M[i] += __shfl_xor(M[i], 1, 64);
        M[i] += __shfl_xor(M[i], 2, 64);
        M[i] += __shfl_xor(M[i], 4, 64);
        M[i] += __shfl_xor(M[i], 8, 64);
    }
    float bt0 = BTv[0], bt1 = BTv[1];
    float bf0 = 0.f, bf1 = 0.f;
#pragma unroll
    for (int it = 0; it < 8; ++it) {
        float q00 = bf0 * bf0, q01 = bf0 * bf1, q11 = bf1 * bf1;
        float s0 = M[0] - (bf0 * M[2] + bf1 * M[3]) + (q00 * M[5] + 2.f * q01 * M[6] + q11 * M[7]);
        float s1 = M[1] - (bf0 * M[3] + bf1 * M[4]) + (q00 * M[6] + 2.f * q01 * M[7] + q11 * M[8]);
        bf0 = bt0 / (1.f + s0);
        bf1 = bt1 / (1.f + s1);
    }
    if (li == 0) { bfs[r][0] = bf0; bfs[r][1] = bf1; }

    // ---- phase 2: register-only weighting of pk ----
#pragma unroll
    for (int c = 0; c < 16; ++c) {
        const float* kp = kpp + 2 * (c * 64 + li * 4);
        float4 kA = *(const float4*)(kp);
        float4 kB = *(const float4*)(kp + 4);
        float pe[4] = {kA.x, kA.z, kB.x, kB.z};
        float qe[4] = {kA.y, kA.w, kB.y, kB.w};
        float ae[4] = {
            b2f((unsigned short)(pk[c][0] & 0xffffu)),
            b2f((unsigned short)(pk[c][0] >> 16)),
            b2f((unsigned short)(pk[c][1] & 0xffffu)),
            b2f((unsigned short)(pk[c][1] >> 16))
        };
        unsigned short rs[4];
#pragma unroll
        for (int e = 0; e < 4; ++e) {
            float x  = bf0 * pe[e] + bf1 * qe[e];
            float wg = x * (x - 1.f) + 1.f;       // 1 - x + x^2
            rs[e] = f2b(ae[e] * wg);
        }
        pk[c][0] = (unsigned int)rs[0] | ((unsigned int)rs[1] << 16);
        pk[c][1] = (unsigned int)rs[2] | ((unsigned int)rs[3] << 16);
    }
    __syncthreads();   // kpp reads done -> lB[0] reusable; bfs visible

    // ---- phase 3: K-loop ----
    const unsigned short* gBp[4];
#pragma unroll
    for (int i = 0; i < 4; ++i) {
        int s = i * 512 + t;
        int n = s >> 3;
        int c = s & 7;
        gBp[i] = Bg + (size_t)n * AD + 8 * (c ^ (n & 7));  // slot s holds chunk (s&7)^(n&7)
    }
    // A write addr: tile chunk li>>1 of row r, half li&1 (swizzled)
    const int aws = (r * 8 + ((li >> 1) ^ (r & 7))) * 8 + (li & 1) * 4;

    // prologue: stage tile 0
#pragma unroll
    for (int i = 0; i < 4; ++i)
        __builtin_amdgcn_global_load_lds(GLB_PTR(gBp[i]), LDS_PTR(&lB[0][(i * 512 + t) * 8]), 16, 0, 0);
    *(uint2*)&lAb[0][aws] = make_uint2(pk[0][0], pk[0][1]);
    __syncthreads();

    f32x4_t acc[2][2];
#pragma unroll
    for (int i = 0; i < 2; ++i)
#pragma unroll
        for (int j = 0; j < 2; ++j) acc[i][j] = (f32x4_t){0.f, 0.f, 0.f, 0.f};

    const int rr = lane & 15, q4 = lane >> 4;

#pragma unroll
    for (int kt = 0; kt < 16; ++kt) {
        const int buf = kt & 1;
        if (kt + 1 < 16) {
#pragma unroll
            for (int i = 0; i < 4; ++i)
                __builtin_amdgcn_global_load_lds(GLB_PTR(gBp[i] + (kt + 1) * 64),
                                                 LDS_PTR(&lB[buf ^ 1][(i * 512 + t) * 8]), 16, 0, 0);
            *(uint2*)&lAb[buf ^ 1][aws] = make_uint2(pk[kt + 1][0], pk[kt + 1][1]);
        }
#pragma unroll
        for (int kk = 0; kk < 2; ++kk) {
            const int cq = kk * 4 + q4;
            bf16x8_t fa[2], fb[2];
#pragma unroll
            for (int i = 0; i < 2; ++i) {
                int m = i * 16 + rr;
                fa[i] = *(const bf16x8_t*)(&lAb[buf][(m * 8 + (cq ^ (m & 7))) * 8]);
            }
#pragma unroll
            for (int j = 0; j < 2; ++j) {
                int n = j * 128 + w * 16 + rr;
                fb[j] = *(const bf16x8_t*)(&lB[buf][(n * 8 + (cq ^ (n & 7))) * 8]);
            }
#pragma unroll
            for (int i = 0; i < 2; ++i)
#pragma unroll
                for (int j = 0; j < 2; ++j)
                    acc[i][j] = __builtin_amdgcn_mfma_f32_16x16x32_bf16(fa[i], fb[j], acc[i][j], 0, 0, 0);
        }
        __syncthreads();   // drains next tile's B loads + lAb write; protects buf reuse
    }

    // ---- epilogue: C/D layout col=lane&15 (n), row=q4*4+reg (m) ----
#pragma unroll
    for (int i = 0; i < 2; ++i) {
#pragma unroll
        for (int rt = 0; rt < 4; ++rt) {
            int ml = i * 16 + q4 * 4 + rt;
            int y  = w * 16 + rr;
            float v = bfs[ml][0] * acc[i][0][rt] + bfs[ml][1] * acc[i][1][rt] + bias[y];
            out[(size_t)(mtile * BM + ml) * YD + y] = v;
        }
    }
}

// =====================================================================
extern "C" void kernel_launch(void* const* d_in, const int* in_sizes, int n_in,
                              void* d_out, int out_size, void* d_ws, size_t ws_size,
                              hipStream_t stream) {
    const float* AT  = (const float*)d_in[0];  // [16384][1024] f32
    const float* Kq  = (const float*)d_in[1];  // [1024][2] f32
    const float* BTv = (const float*)d_in[2];  // [2] f32
    const float* U   = (const float*)d_in[3];  // [2048][128] f32
    const float* bia = (const float*)d_in[4];  // [128] f32
    float* out = (float*)d_out;

    unsigned short* Vt = (unsigned short*)d_ws;   // 512 KB bf16 [256][1024]

    vt_kernel<<<dim3(1024), dim3(256), 0, stream>>>(Kq, U, Vt);
    fused_kernel<<<dim3(NB / BM), dim3(512), 0, stream>>>(AT, Kq, BTv, Vt, bia, out);
}

// Round 7
// 132.110 us; speedup vs baseline: 1.1155x; 1.0088x over previous
//
#include <hip/hip_runtime.h>

// ---------- bf16 helpers (raw ushort representation) ----------
__device__ __forceinline__ unsigned short f2b(float f) {
    unsigned int u = __builtin_bit_cast(unsigned int, f);
    u += 0x7fffu + ((u >> 16) & 1u);   // round-to-nearest-even
    return (unsigned short)(u >> 16);
}

typedef short bf16x8_t __attribute__((ext_vector_type(8)));
typedef float f32x4_t  __attribute__((ext_vector_type(4)));

#define LDS_PTR(p) ((__attribute__((address_space(3))) void*)(p))
#define GLB_PTR(p) ((const __attribute__((address_space(1))) void*)(p))

// Problem dims
#define NB   16384   // batch
#define AD   1024    // A dim
#define YD   128     // output dim
#define ND   256     // GEMM N = 2*YD
#define BM   32      // gemm rows per block

// =====================================================================
// Kernel 1: blocks [0,4096): one wave per row — 9 moments -> closed-form
//   bf fixed point (R2-validated) -> write af bf16 + bff. High occupancy,
//   no LDS: the latency-heavy serial math lives here where 32k waves hide it.
// blocks [4096,5120): Vt[n][a] = Kq[a,j]^2 * u[2a+j][y]  (bf16, K-major).
// =====================================================================
__global__ __launch_bounds__(256) void rowvt_kernel(
    const float* __restrict__ AT,     // [16384][1024] f32
    const float* __restrict__ Kq,     // [1024][2] f32
    const float* __restrict__ BTv,    // [2] f32
    const float* __restrict__ U,      // [2048][128] f32
    unsigned short* __restrict__ afb, // [16384][1024] bf16 out
    unsigned short* __restrict__ Vt,  // [256][1024] bf16 out
    float* __restrict__ bff)          // [16384][2] f32 out
{
    int bx = blockIdx.x;
    if (bx >= NB / 4) {
        int idx = (bx - NB / 4) * 256 + threadIdx.x;   // 0 .. 262143
        int n = idx >> 10;
        int a = idx & 1023;
        int j = n >> 7;
        int y = n & 127;
        float k  = Kq[2 * a + j];
        float uv = U[(size_t)(2 * a + j) * YD + y];
        Vt[idx] = f2b(k * k * uv);
        return;
    }
    int wid  = bx * 4 + (threadIdx.x >> 6);
    int lane = threadIdx.x & 63;
    const float* at = AT + (size_t)wid * AD;

    // lane holds cols a = c*256 + lane*4 + e (coalesced float4s)
    float ta[16], kp0[16], kp1[16];
#pragma unroll
    for (int c = 0; c < 4; ++c) {
        int base = c * 256 + lane * 4;
        float4 av = *(const float4*)(at + base);
        ta[c * 4 + 0] = av.x; ta[c * 4 + 1] = av.y;
        ta[c * 4 + 2] = av.z; ta[c * 4 + 3] = av.w;
        float4 k0 = *(const float4*)(Kq + 2 * base);
        float4 k1 = *(const float4*)(Kq + 2 * base + 4);
        kp0[c * 4 + 0] = k0.x * k0.x; kp1[c * 4 + 0] = k0.y * k0.y;
        kp0[c * 4 + 1] = k0.z * k0.z; kp1[c * 4 + 1] = k0.w * k0.w;
        kp0[c * 4 + 2] = k1.x * k1.x; kp1[c * 4 + 2] = k1.y * k1.y;
        kp0[c * 4 + 3] = k1.z * k1.z; kp1[c * 4 + 3] = k1.w * k1.w;
    }

    // moments: 0:M0 1:M1 2:M00 3:M01 4:M11 5:M000 6:M001 7:M011 8:M111
    float M[9];
#pragma unroll
    for (int i = 0; i < 9; ++i) M[i] = 0.f;
#pragma unroll
    for (int e = 0; e < 16; ++e) {
        float t = ta[e], p = kp0[e], q = kp1[e];
        float u0 = t * p, u1 = t * q;
        M[0] += u0; M[1] += u1;
        float u00 = u0 * p, u01 = u0 * q, u11 = u1 * q;
        M[2] += u00; M[3] += u01; M[4] += u11;
        M[5] += u00 * p; M[6] += u00 * q; M[7] += u01 * q; M[8] += u11 * q;
    }
#pragma unroll
    for (int i = 0; i < 9; ++i) {
        for (int m = 1; m < 64; m <<= 1) M[i] += __shfl_xor(M[i], m, 64);
    }

    float bt0 = BTv[0], bt1 = BTv[1];
    float bf0 = 0.f, bf1 = 0.f;
#pragma unroll
    for (int it = 0; it < 8; ++it) {
        float q00 = bf0 * bf0, q01 = bf0 * bf1, q11 = bf1 * bf1;
        float s0 = M[0] - (bf0 * M[2] + bf1 * M[3]) + (q00 * M[5] + 2.f * q01 * M[6] + q11 * M[7]);
        float s1 = M[1] - (bf0 * M[3] + bf1 * M[4]) + (q00 * M[6] + 2.f * q01 * M[7] + q11 * M[8]);
        bf0 = bt0 / (1.f + s0);
        bf1 = bt1 / (1.f + s1);
    }
    if (lane == 0) { bff[(size_t)wid * 2] = bf0; bff[(size_t)wid * 2 + 1] = bf1; }

    // af = AT / (1 + bf0*kp0 + bf1*kp1), one bf16 rounding (R3-identical)
    unsigned short* ao = afb + (size_t)wid * AD;
#pragma unroll
    for (int c = 0; c < 4; ++c) {
        unsigned short r[4];
#pragma unroll
        for (int e = 0; e < 4; ++e) {
            int idx = c * 4 + e;
            r[e] = f2b(ta[idx] / (1.f + bf0 * kp0[idx] + bf1 * kp1[idx]));
        }
        *(ushort4*)(ao + c * 256 + lane * 4) = make_ushort4(r[0], r[1], r[2], r[3]);
    }
}

// =====================================================================
// Kernel 2: pure GEMM + fused combine (R6 K-loop, pre-loop reduced to
// 16 coalesced uint2 loads of ready bf16 af into registers).
//   out[m][y] = bf0[m]*G[m][y] + bf1[m]*G[m][y+128] + bias[y]
// BM=32, BN=256(full), BK=64; 512 blocks, 512 thr (8 waves).
// LDS: lB dbuf 64K + lAb dbuf 8K + bfs 256B = 72.25K -> 2 blocks/CU.
// =====================================================================
__global__ __launch_bounds__(512, 2) void gemm_kernel(
    const unsigned short* __restrict__ Ag,   // af [16384][1024] bf16
    const unsigned short* __restrict__ Bg,   // Vt [256][1024] bf16
    const float* __restrict__ bff,           // [16384][2]
    const float* __restrict__ bias,          // [128]
    float* __restrict__ out)                 // [16384][128] f32
{
    __shared__ __align__(16) unsigned short lB[2][256 * 64];  // 64 KB
    __shared__ __align__(16) unsigned short lAb[2][32 * 64];  // 8 KB
    __shared__ float bfs[BM][2];                              // 256 B

    const int t     = threadIdx.x;
    const int mtile = blockIdx.x;   // 0..511
    const int r     = t >> 4;       // row 0..31
    const int li    = t & 15;
    const int lane  = t & 63;
    const int w     = t >> 6;       // wave 0..7

    // ---- pre-loop: af -> pk registers (chunk c == K-tile c), bfs, B ptrs ----
    const unsigned short* aRow = Ag + (size_t)(mtile * BM + r) * AD + li * 4;
    unsigned int pk[16][2];
#pragma unroll
    for (int c = 0; c < 16; ++c) {
        uint2 v = *(const uint2*)(aRow + c * 64);
        pk[c][0] = v.x; pk[c][1] = v.y;
    }
    if (t < BM) *(float2*)&bfs[t][0] = *(const float2*)(bff + (size_t)(mtile * BM + t) * 2);

    const unsigned short* gBp[4];
#pragma unroll
    for (int i = 0; i < 4; ++i) {
        int s = i * 512 + t;
        int n = s >> 3;
        int c = s & 7;
        gBp[i] = Bg + (size_t)n * AD + 8 * (c ^ (n & 7));  // slot s holds chunk (s&7)^(n&7)
    }
    // A write addr: tile chunk li>>1 of row r, half li&1 (swizzled)
    const int aws = (r * 8 + ((li >> 1) ^ (r & 7))) * 8 + (li & 1) * 4;

    // prologue: stage tile 0
#pragma unroll
    for (int i = 0; i < 4; ++i)
        __builtin_amdgcn_global_load_lds(GLB_PTR(gBp[i]), LDS_PTR(&lB[0][(i * 512 + t) * 8]), 16, 0, 0);
    *(uint2*)&lAb[0][aws] = make_uint2(pk[0][0], pk[0][1]);
    __syncthreads();

    f32x4_t acc[2][2];
#pragma unroll
    for (int i = 0; i < 2; ++i)
#pragma unroll
        for (int j = 0; j < 2; ++j) acc[i][j] = (f32x4_t){0.f, 0.f, 0.f, 0.f};

    const int rr = lane & 15, q4 = lane >> 4;

#pragma unroll
    for (int kt = 0; kt < 16; ++kt) {
        const int buf = kt & 1;
        if (kt + 1 < 16) {
#pragma unroll
            for (int i = 0; i < 4; ++i)
                __builtin_amdgcn_global_load_lds(GLB_PTR(gBp[i] + (kt + 1) * 64),
                                                 LDS_PTR(&lB[buf ^ 1][(i * 512 + t) * 8]), 16, 0, 0);
            *(uint2*)&lAb[buf ^ 1][aws] = make_uint2(pk[kt + 1][0], pk[kt + 1][1]);
        }
#pragma unroll
        for (int kk = 0; kk < 2; ++kk) {
            const int cq = kk * 4 + q4;
            bf16x8_t fa[2], fb[2];
#pragma unroll
            for (int i = 0; i < 2; ++i) {
                int m = i * 16 + rr;
                fa[i] = *(const bf16x8_t*)(&lAb[buf][(m * 8 + (cq ^ (m & 7))) * 8]);
            }
#pragma unroll
            for (int j = 0; j < 2; ++j) {
                int n = j * 128 + w * 16 + rr;
                fb[j] = *(const bf16x8_t*)(&lB[buf][(n * 8 + (cq ^ (n & 7))) * 8]);
            }
#pragma unroll
            for (int i = 0; i < 2; ++i)
#pragma unroll
                for (int j = 0; j < 2; ++j)
                    acc[i][j] = __builtin_amdgcn_mfma_f32_16x16x32_bf16(fa[i], fb[j], acc[i][j], 0, 0, 0);
        }
        __syncthreads();   // drains next tile's B loads + lAb write; protects buf reuse
    }

    // ---- epilogue: C/D layout col=lane&15 (n), row=q4*4+reg (m) ----
#pragma unroll
    for (int i = 0; i < 2; ++i) {
#pragma unroll
        for (int rt = 0; rt < 4; ++rt) {
            int ml = i * 16 + q4 * 4 + rt;
            int y  = w * 16 + rr;
            float v = bfs[ml][0] * acc[i][0][rt] + bfs[ml][1] * acc[i][1][rt] + bias[y];
            out[(size_t)(mtile * BM + ml) * YD + y] = v;
        }
    }
}

// =====================================================================
extern "C" void kernel_launch(void* const* d_in, const int* in_sizes, int n_in,
                              void* d_out, int out_size, void* d_ws, size_t ws_size,
                              hipStream_t stream) {
    const float* AT  = (const float*)d_in[0];  // [16384][1024] f32
    const float* Kq  = (const float*)d_in[1];  // [1024][2] f32
    const float* BTv = (const float*)d_in[2];  // [2] f32
    const float* U   = (const float*)d_in[3];  // [2048][128] f32
    const float* bia = (const float*)d_in[4];  // [128] f32
    float* out = (float*)d_out;

    char* ws = (char*)d_ws;
    unsigned short* afb = (unsigned short*)(ws);             // 32 MB  bf16 [16384][1024]
    unsigned short* Vt  = (unsigned short*)(ws + 33554432);  // 512 KB bf16 [256][1024]
    float*          bff = (float*)(ws + 34078720);           // 128 KB f32  [16384][2]

    rowvt_kernel<<<dim3(NB / 4 + 1024), dim3(256), 0, stream>>>(AT, Kq, BTv, U, afb, Vt, bff);
    gemm_kernel<<<dim3(NB / BM), dim3(512), 0, stream>>>(afb, Vt, bff, bia, out);
}